// Round 12
// baseline (142.044 us; speedup 1.0000x reference)
//
#include <hip/hip_runtime.h>

// ---------------------------------------------------------------------------
// PointAttentionEncoder1D, Round 22 = R21 + s_setprio around MFMA chains.
//  R21 post-mortem: bank conflicts 780K->140K as predicted, time flat ->
//  conflicts were hidden; keep the LDS transport (cleaner counters, equal
//  main). Main pinned ~60.4us across R19/R20/R21; VALUBusy 55 + MfmaUtil 24
//  = 79% combined issue; occupancy pinned ~2.3 blocks/CU; all conventional
//  levers probed (occupancy x3 fail, VALU diet saturated, ILP hurts,
//  fold banked, transport neutral).
//  R22 lever: guide m185-m191 -- setprio(1) around MFMA clusters gains
//  +4-7% when waves run INDEPENDENT phases (attn-like; hurts only in
//  barrier-lockstep GEMM). Our 4 waves/block run barrier-free tile loops:
//  one wave's S1-S4 MFMA chain overlaps neighbors' softmax VALU. Raising
//  MFMA-phase priority compresses the serial chain. Zero correctness risk.
//  Pre-commitment: if main >= 60us, declare practical floor next round.
//  Everything else R21 verbatim.
// ---------------------------------------------------------------------------

constexpr int PPB = 15;
constexpr float LOG2E = 1.44269504088896340736f;

typedef __attribute__((ext_vector_type(8))) short bf8;   // K32 A/B frag
typedef __attribute__((ext_vector_type(4))) float f4;
typedef __attribute__((ext_vector_type(2))) float f2;
typedef __attribute__((ext_vector_type(2))) __bf16 bfp2;

// one v_cvt_pk_bf16_f32: [bf16(b) : bf16(a)], RNE (fptrunc semantics)
__device__ __forceinline__ unsigned int pkbf(float a, float b) {
  f2 v; v[0] = a; v[1] = b;
  const bfp2 r = __builtin_convertvector(v, bfp2);
  return __builtin_bit_cast(unsigned int, r);
}
__device__ __forceinline__ unsigned short us16(float a) {
  return (unsigned short)((__builtin_bit_cast(unsigned int, a) + 0x8000u) >> 16);
}
__device__ __forceinline__ bf8 mkbf8(const f4& a, const f4& b) {
  uint4 u;
  u.x = pkbf(a[0], a[1]); u.y = pkbf(a[2], a[3]);
  u.z = pkbf(b[0], b[1]); u.w = pkbf(b[2], b[3]);
  return __builtin_bit_cast(bf8, u);
}
// lrelu: slope-mul + elementwise max -> v_pk_mul_f32 + v_pk_max_f32 pairs
__device__ __forceinline__ f4 lrelu4(const f4& v) {
  return __builtin_elementwise_max(v, v * 0.01f);
}
__device__ __forceinline__ f2 lo2(const f4& v) { f2 r; r[0] = v[0]; r[1] = v[1]; return r; }
__device__ __forceinline__ f2 hi2(const f4& v) { f2 r; r[0] = v[2]; r[1] = v[3]; return r; }
// Schraudolph 2^x (R15-proven)
__device__ __forceinline__ float exp2appx(float x) {
  const float t = __builtin_fmaf(x, 8388608.0f, 1064992232.0f);
  return __builtin_bit_cast(float, (int)t);
}
__device__ __forceinline__ f4 mfma32(bf8 a, bf8 b, f4 c) {
  return __builtin_amdgcn_mfma_f32_16x16x32_bf16(a, b, c, 0, 0, 0);
}

// chunk-pair slot order: frag element (q, j) holds logical k = slotk(q,j)
__device__ __forceinline__ int slotk(int q, int j) {
  return (j < 4) ? (q * 4 + j) : (16 + q * 4 + (j - 4));
}

// ---------------- virtual weight matrices (proven R5-R21) -------------------
// input row = [x(3) | fea(3) | c(3) | 1 | 0...]
__device__ __forceinline__ float w1v(const float* mw1, const float* mb1,
                                     int s, int k, int n) {
  const int cb = n >> 4, cc = n & 15;
  const int sk = s ? 1 : 3, sv = s ? 2 : 4;
  if (k < 3)  return cb == 0 ? mw1[sk * 48 + k * 16 + cc]
                   : (cb == 1 ? mw1[sv * 48 + k * 16 + cc] : 0.f);
  if (k < 6)  return cb == 2 ? mw1[5 * 48 + (k - 3) * 16 + cc] : 0.f;
  if (k < 9)  return cb == 3 ? mw1[0 * 48 + (k - 6) * 16 + cc] : 0.f;
  if (k == 9) {
    const int m = (cb == 0) ? sk : (cb == 1) ? sv : (cb == 2) ? 5 : 0;
    return mb1[m * 16 + cc];
  }
  return 0.f;
}
__device__ __forceinline__ float w2v(const float* mw2, int s, int k, int n) {
  const int sk = s ? 1 : 3, sv = s ? 2 : 4;
  if (n < 32) {  // w = q - k + pos
    if (k < 16)            return -mw2[sk * 512 + k * 32 + n];
    if (k >= 32 && k < 48) return  mw2[5 * 512 + (k - 32) * 32 + n];
    if (k >= 48)           return  mw2[0 * 512 + (k - 48) * 32 + n];
    return 0.f;
  } else {       // vp = v + pos
    const int cc = n - 32;
    if (k >= 16 && k < 32) return mw2[sv * 512 + (k - 16) * 32 + cc];
    if (k >= 32 && k < 48) return mw2[5 * 512 + (k - 32) * 32 + cc];
    return 0.f;
  }
}

// ws16 (shorts), all K32 frags of 512 shorts, element [f*512 + lane*8 + j]:
//  [0,4096)      W1^T  f = s*4+c            k = q*8+j (matches bx layout)
//  [4096,12288)  W2^T  f = 8+s*8+mc*2+kc2   k = kc2*32+slotk, n = mc*16+l
//                      (runtime uses only mc=2,3 = vp part)
//  [12288,14336) WP1^T f = 24+mc            (legacy, unused at runtime)
//  [14336,16384) WP2^T f = 28+mc2*2+kc2     k = kc2*32+slotk, n = mc2*16+l, *LOG2E
//  [16384,24576) WC    f = 32+s*8+mc*2+kc2  k = kc2*32+slotk, m = mc*16+l
//                      WC[s][k][m] = sum_n w2v(s,k,n<32)*ww1[n*64+m]
// wsf (floats @ byte 49152):
//  [0,128)   [bw_o(32)|bvp_o(32)|bw_c(32)|bvp_c(32)]  (bw legacy-kept)
//  [128,256) b1p[s][m] = wb1[m] + sum_n bw[s][n]*ww1[n*64+m]
__global__ void prep_kernel(const float* __restrict__ mw1, const float* __restrict__ mb1,
                            const float* __restrict__ mw2, const float* __restrict__ mb2,
                            const float* __restrict__ ww1, const float* __restrict__ ww2,
                            const float* __restrict__ wb1,
                            unsigned short* __restrict__ ws16, float* __restrict__ wsf) {
  if (blockIdx.x < 9) {
    const int tid = blockIdx.x * 256 + threadIdx.x;
    const int lane = tid & 63, q = lane >> 4, l = lane & 15;
    if (tid < 2048) {
      const int f = tid >> 6;
      for (int j = 0; j < 8; j++) {
        float v;
        if (f < 8) {
          const int s = f >> 2, c = f & 3;
          v = w1v(mw1, mb1, s, q * 8 + j, c * 16 + l);
        } else if (f < 24) {
          const int g = f - 8, s = g >> 3, mc = (g >> 1) & 3, kc2 = g & 1;
          v = w2v(mw2, s, kc2 * 32 + slotk(q, j), mc * 16 + l);
        } else if (f < 28) {
          const int mc = f - 24;
          v = ww1[slotk(q, j) * 64 + mc * 16 + l];
        } else {
          const int g = f - 28, mc2 = g >> 1, kc2 = g & 1;
          v = ww2[(kc2 * 32 + slotk(q, j)) * 32 + mc2 * 16 + l] * LOG2E;
        }
        ws16[f * 512 + lane * 8 + j] = us16(v);
      }
    } else if (tid < 2176) {
      const int t2 = tid - 2048, grp = t2 >> 5, cc = t2 & 31;
      float v;
      if (grp == 0)      v = mb2[cc] - mb2[96 + cc] + mb2[160 + cc];   // bw other
      else if (grp == 1) v = mb2[128 + cc] + mb2[160 + cc];            // bvp other
      else if (grp == 2) v = mb2[cc] - mb2[32 + cc] + mb2[160 + cc];   // bw center
      else               v = mb2[64 + cc] + mb2[160 + cc];             // bvp center
      wsf[grp * 32 + cc] = v;
    } else if (tid < 2304) {
      // b1p[s][m] = wb1[m] + sum_n bw[s][n]*ww1[n*64+m]
      const int t2 = tid - 2176, s = t2 >> 6, m = t2 & 63;
      float acc = wb1[m];
#pragma unroll
      for (int n = 0; n < 32; n++) {
        const float bwn = s == 0 ? (mb2[n] - mb2[96 + n] + mb2[160 + n])
                                 : (mb2[n] - mb2[32 + n] + mb2[160 + n]);
        acc = __builtin_fmaf(bwn, ww1[n * 64 + m], acc);
      }
      wsf[128 + s * 64 + m] = acc;
    }
  } else {
    // WC: one thread per output element. 8192 elements over 32 blocks.
    // k-branch hoisted: w2v(s,k,n<32) = sign * mw2row[n] (contiguous) or 0.
    const int e = (blockIdx.x - 9) * 256 + threadIdx.x;   // 0..8191
    const int g = e >> 9;                                  // frag 0..15
    const int r = e & 511;                                 // element in frag
    const int lane = r >> 3, j = r & 7;
    const int q = lane >> 4, l = lane & 15;
    const int s = g >> 3, mc = (g >> 1) & 3, kc2 = g & 1;
    const int k = kc2 * 32 + slotk(q, j);
    const int m = mc * 16 + l;
    float acc = 0.f;
    if (k < 16 || k >= 32) {
      const int sk = s ? 1 : 3;
      const float* src = (k < 16) ? (mw2 + sk * 512 + k * 32)
                       : (k < 48) ? (mw2 + 5 * 512 + (k - 32) * 32)
                                  : (mw2 + 0 * 512 + (k - 48) * 32);
      const float* wrow = ww1 + m;
#pragma unroll
      for (int n = 0; n < 32; n++)
        acc = __builtin_fmaf(src[n], wrow[n * 64], acc);
      if (k < 16) acc = -acc;   // sign applied once (bit-identical to R19 sum)
    }
    ws16[(32 + g) * 512 + r] = us16(acc);
  }
}

// ---------------- main kernel ----------------------------------------------
__global__ __launch_bounds__(256, 2) void point_attn_kernel(
    const float* __restrict__ center, const float* __restrict__ other,
    const float* __restrict__ wb2,
    const unsigned short* __restrict__ ws16, const float* __restrict__ wsf,
    float* __restrict__ out, int P) {
  // pr rows: dwords 0..31 = products (32 ch), dwords 32..35 = staged
  // {d0,d1,d2,d3} row-transport (replaces bpermute gathers).
  __shared__ float pr[256 * 36];
  __shared__ unsigned int d4tab[256];   // staged d4 per row

  const int t = threadIdx.x, lane = t & 63, wv = t >> 6;
  const int q = lane >> 4, l = lane & 15;

  // ---- stage this thread's row into LDS (row r = t) ----
  {
    const int isC = (t >= 240);
    const int pt = isC ? (t - 240) : (t >> 4);
    int p = blockIdx.x * PPB + pt;
    p = p < P ? p : P - 1;
    const float c0 = center[(size_t)p * 3 + 0];
    const float c1 = center[(size_t)p * 3 + 1];
    const float c2 = center[(size_t)p * 3 + 2];
    const float* op = other + ((size_t)p * 16 + (t & 15)) * 3;
    const float o0 = op[0], o1 = op[1], o2 = op[2];
    const float x0 = isC ? c0 : o0, x1 = isC ? c1 : o1, x2 = isC ? c2 : o2;
    const float g0 = c0 - x0, g1 = c1 - x1, g2 = c2 - x2;  // 0 for center rows
    uint4 dd;
    dd.x = pkbf(x0, x1); dd.y = pkbf(x2, g0); dd.z = pkbf(g1, g2);
    dd.w = pkbf(c0, c1);
    *(uint4*)&pr[t * 36 + 32] = dd;          // ds_write_b128
    d4tab[t] = pkbf(c2, 1.0f);               // ds_write_b32
  }
  // No barrier needed: each wave's tiles read only rows staged by the SAME
  // wave (wave wv owns rows wv*64..wv*64+63; tile 15 rows 240..255 = wave 3).

  // ---- weight/bias registers ----
  bf8 W1[4], W2v[2][2], WC[4][2], P2[2][2];
  f4 bvp[2], b1p[4], b2f[2];

  auto loadSet = [&](int s) {
#pragma unroll
    for (int c = 0; c < 4; c++)
      W1[c] = *(const bf8*)(ws16 + ((s * 4 + c) * 512 + lane * 8));
#pragma unroll
    for (int mc = 0; mc < 2; mc++)
#pragma unroll
      for (int kc2 = 0; kc2 < 2; kc2++)
        W2v[mc][kc2] = *(const bf8*)(ws16 + ((8 + s * 8 + (mc + 2) * 2 + kc2) * 512 + lane * 8));
#pragma unroll
    for (int mc = 0; mc < 4; mc++)
#pragma unroll
      for (int kc2 = 0; kc2 < 2; kc2++)
        WC[mc][kc2] = *(const bf8*)(ws16 + ((32 + s * 8 + mc * 2 + kc2) * 512 + lane * 8));
#pragma unroll
    for (int mc = 0; mc < 2; mc++)
      bvp[mc] = *(const f4*)(wsf + s * 64 + 32 + mc * 16 + q * 4);
#pragma unroll
    for (int mc = 0; mc < 4; mc++)
      b1p[mc] = *(const f4*)(wsf + 128 + s * 64 + mc * 16 + q * 4);
  };

  loadSet(wv == 3 ? 1 : 0);
#pragma unroll
  for (int mc2 = 0; mc2 < 2; mc2++)
#pragma unroll
    for (int kc2 = 0; kc2 < 2; kc2++)
      P2[mc2][kc2] = *(const bf8*)(ws16 + ((28 + mc2 * 2 + kc2) * 512 + lane * 8));
#pragma unroll
  for (int mc2 = 0; mc2 < 2; mc2++) {
    const f4 b = *(const f4*)(wb2 + mc2 * 16 + q * 4);
#pragma unroll
    for (int j = 0; j < 4; j++) b2f[mc2][j] = b[j] * LOG2E;
  }

  auto computeTile = [&](int T) {
    // row transport: b128 read of {d0..d3} + b32 read of d4, then select.
    const int row = T * 16 + l;
    const uint4 g = *(const uint4*)&pr[row * 36 + 32];
    const unsigned int s4 = d4tab[row];
    uint4 bu;
    bu.x = q == 0 ? g.x : (q == 1 ? s4 : 0u);
    bu.y = q == 0 ? g.y : 0u;
    bu.z = q == 0 ? g.z : 0u;
    bu.w = q == 0 ? g.w : 0u;
    const bf8 bx = __builtin_bit_cast(bf8, bu);
    const f4 fzero = {0.f, 0.f, 0.f, 0.f};

    // MFMA-chain phase: favored by the CU scheduler while other waves are
    // in their softmax/pack VALU phase (independent, barrier-free waves --
    // the m191-positive structure; NOT barrier-lockstep).
    __builtin_amdgcn_s_setprio(1);

    // S1: H^T chunks = [h_k|h_v|h_pos|h_q] (K32, bias in virtual k=9 row)
    f4 D1[4];
#pragma unroll
    for (int c = 0; c < 4; c++)
      D1[c] = lrelu4(mfma32(W1[c], bx, fzero));
    const bf8 hlo = mkbf8(D1[0], D1[1]);
    const bf8 hhi = mkbf8(D1[2], D1[3]);

    // S2vp: vp^T = W2vp^T x H^T, bias in C (independent of S3')
    f4 vpv[2];
#pragma unroll
    for (int mc = 0; mc < 2; mc++) {
      f4 acc = mfma32(W2v[mc][0], hlo, bvp[mc]);
      vpv[mc] = mfma32(W2v[mc][1], hhi, acc);
    }

    // S3' (fused): Hwp^T = WC^T x H^T + b1p  (WP1 folded into W2w in prep)
    f4 h2[4];
#pragma unroll
    for (int mc = 0; mc < 4; mc++) {
      f4 acc = mfma32(WC[mc][1], hhi, b1p[mc]);
      acc = mfma32(WC[mc][0], hlo, acc);
      h2[mc] = lrelu4(acc);
    }
    const bf8 h2lo = mkbf8(h2[0], h2[1]);
    const bf8 h2hi = mkbf8(h2[2], h2[3]);

    // S4: fw^T (log2 domain) = WP2^T x Hwp^T, bias in C
    f4 fw[2];
#pragma unroll
    for (int mc2 = 0; mc2 < 2; mc2++) {
      f4 acc = mfma32(P2[mc2][0], h2lo, b2f[mc2]);
      fw[mc2] = mfma32(P2[mc2][1], h2hi, acc);
    }

    __builtin_amdgcn_s_setprio(0);   // softmax/product phase at normal prio

    // softmax over 32 channels of row l, base-2 domain, no max-subtraction
    f4 ex0, ex1;
#pragma unroll
    for (int j = 0; j < 4; j++) {
      ex0[j] = exp2appx(fw[0][j]);
      ex1[j] = exp2appx(fw[1][j]);
    }
    const f2 sA = lo2(ex0) + hi2(ex0);
    const f2 sB = lo2(ex1) + hi2(ex1);
    const f2 sC = sA + sB;
    float sum = sC[0] + sC[1];
    sum += __shfl_xor(sum, 16);
    sum += __shfl_xor(sum, 32);
    const float inv = __builtin_amdgcn_rcpf(sum);

    f4 iv; iv[0] = inv; iv[1] = inv; iv[2] = inv; iv[3] = inv;
    const f4 p0 = ex0 * iv * vpv[0];   // packed f32 muls
    const f4 p1 = ex1 * iv * vpv[1];
    *(f4*)&pr[(T * 16 + l) * 36 + q * 4] = p0;        // channels q*4..
    *(f4*)&pr[(T * 16 + l) * 36 + 16 + q * 4] = p1;   // channels 16+q*4..
  };

  // wave 3 does the center tile (15) first with the center weight set
  if (wv == 3) {
    computeTile(15);
    loadSet(0);
    computeTile(12); computeTile(13); computeTile(14);
  } else {
    computeTile(wv * 4 + 0); computeTile(wv * 4 + 1);
    computeTile(wv * 4 + 2); computeTile(wv * 4 + 3);
  }

  __syncthreads();

  // final reduce: 17 rows per point, f2-vectorized (ds_read_b64 + pk_add).
  if (t < 240) {
    const int pp = t >> 4, cp = t & 15;
    f2 s = *(const f2*)&pr[(240 + pp) * 36 + cp * 2];
#pragma unroll
    for (int r2 = 0; r2 < 16; r2++)
      s += *(const f2*)&pr[(pp * 16 + r2) * 36 + cp * 2];
    const int gp = blockIdx.x * PPB + pp;
    if (gp < P) *(f2*)&out[(size_t)gp * 32 + cp * 2] = s;
  }
}

extern "C" void kernel_launch(void* const* d_in, const int* in_sizes, int n_in,
                              void* d_out, int out_size, void* d_ws, size_t ws_size,
                              hipStream_t stream) {
  const float* center = (const float*)d_in[0];
  const float* other  = (const float*)d_in[1];
  unsigned short* ws16 = (unsigned short*)d_ws;
  float* wsf = (float*)((char*)d_ws + 49152);

  prep_kernel<<<41, 256, 0, stream>>>(
      (const float*)d_in[2], (const float*)d_in[3],
      (const float*)d_in[4], (const float*)d_in[5],
      (const float*)d_in[6], (const float*)d_in[8],
      (const float*)d_in[7], ws16, wsf);

  const int P = in_sizes[0] / 3;
  const int blocks = (P + PPB - 1) / PPB;
  point_attn_kernel<<<blocks, 256, 0, stream>>>(
      center, other,
      (const float*)d_in[9],
      ws16, wsf, (float*)d_out, P);
}

// Round 13
// 135.115 us; speedup vs baseline: 1.0513x; 1.0513x over previous
//
#include <hip/hip_runtime.h>

// ---------------------------------------------------------------------------
// PointAttentionEncoder1D, Round 23 = R21 restored (best-known kernel).
//  R22 post-mortem: s_setprio(1) around MFMA chains HURT (main 60.4->65.0us,
//  bank conflicts 140K->1.42M, MfmaUtil 24->21.5). Mechanism: priority boost
//  de-interleaves the natural phase rotation -> waves convoy into the same
//  phase and their DS/softmax sections collide. m191's attn transfer failed
//  because our waves share an LDS working set (attn blocks were independent).
//  setprio = proven negative for this structure.
//  Final state of the probe matrix: occupancy (3x pinned at ~9 waves/CU),
//  VALU diet (saturated R15), intra-wave ILP (VGPR regression R12), stage
//  folding (banked R17: WP1 into W2w), prep cost (banked R20), row transport
//  (neutral-clean R21), scheduler hints (negative R22). Practical floor:
//  main ~60.4us, combined issue ~79% (VALUBusy ~55 + MfmaUtil ~24), HBM 5%.
//  This round restores R21 verbatim to bank the best configuration.
// ---------------------------------------------------------------------------

constexpr int PPB = 15;
constexpr float LOG2E = 1.44269504088896340736f;

typedef __attribute__((ext_vector_type(8))) short bf8;   // K32 A/B frag
typedef __attribute__((ext_vector_type(4))) float f4;
typedef __attribute__((ext_vector_type(2))) float f2;
typedef __attribute__((ext_vector_type(2))) __bf16 bfp2;

// one v_cvt_pk_bf16_f32: [bf16(b) : bf16(a)], RNE (fptrunc semantics)
__device__ __forceinline__ unsigned int pkbf(float a, float b) {
  f2 v; v[0] = a; v[1] = b;
  const bfp2 r = __builtin_convertvector(v, bfp2);
  return __builtin_bit_cast(unsigned int, r);
}
__device__ __forceinline__ unsigned short us16(float a) {
  return (unsigned short)((__builtin_bit_cast(unsigned int, a) + 0x8000u) >> 16);
}
__device__ __forceinline__ bf8 mkbf8(const f4& a, const f4& b) {
  uint4 u;
  u.x = pkbf(a[0], a[1]); u.y = pkbf(a[2], a[3]);
  u.z = pkbf(b[0], b[1]); u.w = pkbf(b[2], b[3]);
  return __builtin_bit_cast(bf8, u);
}
// lrelu: slope-mul + elementwise max -> v_pk_mul_f32 + v_pk_max_f32 pairs
__device__ __forceinline__ f4 lrelu4(const f4& v) {
  return __builtin_elementwise_max(v, v * 0.01f);
}
__device__ __forceinline__ f2 lo2(const f4& v) { f2 r; r[0] = v[0]; r[1] = v[1]; return r; }
__device__ __forceinline__ f2 hi2(const f4& v) { f2 r; r[0] = v[2]; r[1] = v[3]; return r; }
// Schraudolph 2^x (R15-proven)
__device__ __forceinline__ float exp2appx(float x) {
  const float t = __builtin_fmaf(x, 8388608.0f, 1064992232.0f);
  return __builtin_bit_cast(float, (int)t);
}
__device__ __forceinline__ f4 mfma32(bf8 a, bf8 b, f4 c) {
  return __builtin_amdgcn_mfma_f32_16x16x32_bf16(a, b, c, 0, 0, 0);
}

// chunk-pair slot order: frag element (q, j) holds logical k = slotk(q,j)
__device__ __forceinline__ int slotk(int q, int j) {
  return (j < 4) ? (q * 4 + j) : (16 + q * 4 + (j - 4));
}

// ---------------- virtual weight matrices (proven R5-R21) -------------------
// input row = [x(3) | fea(3) | c(3) | 1 | 0...]
__device__ __forceinline__ float w1v(const float* mw1, const float* mb1,
                                     int s, int k, int n) {
  const int cb = n >> 4, cc = n & 15;
  const int sk = s ? 1 : 3, sv = s ? 2 : 4;
  if (k < 3)  return cb == 0 ? mw1[sk * 48 + k * 16 + cc]
                   : (cb == 1 ? mw1[sv * 48 + k * 16 + cc] : 0.f);
  if (k < 6)  return cb == 2 ? mw1[5 * 48 + (k - 3) * 16 + cc] : 0.f;
  if (k < 9)  return cb == 3 ? mw1[0 * 48 + (k - 6) * 16 + cc] : 0.f;
  if (k == 9) {
    const int m = (cb == 0) ? sk : (cb == 1) ? sv : (cb == 2) ? 5 : 0;
    return mb1[m * 16 + cc];
  }
  return 0.f;
}
__device__ __forceinline__ float w2v(const float* mw2, int s, int k, int n) {
  const int sk = s ? 1 : 3, sv = s ? 2 : 4;
  if (n < 32) {  // w = q - k + pos
    if (k < 16)            return -mw2[sk * 512 + k * 32 + n];
    if (k >= 32 && k < 48) return  mw2[5 * 512 + (k - 32) * 32 + n];
    if (k >= 48)           return  mw2[0 * 512 + (k - 48) * 32 + n];
    return 0.f;
  } else {       // vp = v + pos
    const int cc = n - 32;
    if (k >= 16 && k < 32) return mw2[sv * 512 + (k - 16) * 32 + cc];
    if (k >= 32 && k < 48) return mw2[5 * 512 + (k - 32) * 32 + cc];
    return 0.f;
  }
}

// ws16 (shorts), all K32 frags of 512 shorts, element [f*512 + lane*8 + j]:
//  [0,4096)      W1^T  f = s*4+c            k = q*8+j (matches bx layout)
//  [4096,12288)  W2^T  f = 8+s*8+mc*2+kc2   k = kc2*32+slotk, n = mc*16+l
//                      (runtime uses only mc=2,3 = vp part)
//  [12288,14336) WP1^T f = 24+mc            (legacy, unused at runtime)
//  [14336,16384) WP2^T f = 28+mc2*2+kc2     k = kc2*32+slotk, n = mc2*16+l, *LOG2E
//  [16384,24576) WC    f = 32+s*8+mc*2+kc2  k = kc2*32+slotk, m = mc*16+l
//                      WC[s][k][m] = sum_n w2v(s,k,n<32)*ww1[n*64+m]
// wsf (floats @ byte 49152):
//  [0,128)   [bw_o(32)|bvp_o(32)|bw_c(32)|bvp_c(32)]  (bw legacy-kept)
//  [128,256) b1p[s][m] = wb1[m] + sum_n bw[s][n]*ww1[n*64+m]
__global__ void prep_kernel(const float* __restrict__ mw1, const float* __restrict__ mb1,
                            const float* __restrict__ mw2, const float* __restrict__ mb2,
                            const float* __restrict__ ww1, const float* __restrict__ ww2,
                            const float* __restrict__ wb1,
                            unsigned short* __restrict__ ws16, float* __restrict__ wsf) {
  if (blockIdx.x < 9) {
    const int tid = blockIdx.x * 256 + threadIdx.x;
    const int lane = tid & 63, q = lane >> 4, l = lane & 15;
    if (tid < 2048) {
      const int f = tid >> 6;
      for (int j = 0; j < 8; j++) {
        float v;
        if (f < 8) {
          const int s = f >> 2, c = f & 3;
          v = w1v(mw1, mb1, s, q * 8 + j, c * 16 + l);
        } else if (f < 24) {
          const int g = f - 8, s = g >> 3, mc = (g >> 1) & 3, kc2 = g & 1;
          v = w2v(mw2, s, kc2 * 32 + slotk(q, j), mc * 16 + l);
        } else if (f < 28) {
          const int mc = f - 24;
          v = ww1[slotk(q, j) * 64 + mc * 16 + l];
        } else {
          const int g = f - 28, mc2 = g >> 1, kc2 = g & 1;
          v = ww2[(kc2 * 32 + slotk(q, j)) * 32 + mc2 * 16 + l] * LOG2E;
        }
        ws16[f * 512 + lane * 8 + j] = us16(v);
      }
    } else if (tid < 2176) {
      const int t2 = tid - 2048, grp = t2 >> 5, cc = t2 & 31;
      float v;
      if (grp == 0)      v = mb2[cc] - mb2[96 + cc] + mb2[160 + cc];   // bw other
      else if (grp == 1) v = mb2[128 + cc] + mb2[160 + cc];            // bvp other
      else if (grp == 2) v = mb2[cc] - mb2[32 + cc] + mb2[160 + cc];   // bw center
      else               v = mb2[64 + cc] + mb2[160 + cc];             // bvp center
      wsf[grp * 32 + cc] = v;
    } else if (tid < 2304) {
      // b1p[s][m] = wb1[m] + sum_n bw[s][n]*ww1[n*64+m]
      const int t2 = tid - 2176, s = t2 >> 6, m = t2 & 63;
      float acc = wb1[m];
#pragma unroll
      for (int n = 0; n < 32; n++) {
        const float bwn = s == 0 ? (mb2[n] - mb2[96 + n] + mb2[160 + n])
                                 : (mb2[n] - mb2[32 + n] + mb2[160 + n]);
        acc = __builtin_fmaf(bwn, ww1[n * 64 + m], acc);
      }
      wsf[128 + s * 64 + m] = acc;
    }
  } else {
    // WC: one thread per output element. 8192 elements over 32 blocks.
    // k-branch hoisted: w2v(s,k,n<32) = sign * mw2row[n] (contiguous) or 0.
    const int e = (blockIdx.x - 9) * 256 + threadIdx.x;   // 0..8191
    const int g = e >> 9;                                  // frag 0..15
    const int r = e & 511;                                 // element in frag
    const int lane = r >> 3, j = r & 7;
    const int q = lane >> 4, l = lane & 15;
    const int s = g >> 3, mc = (g >> 1) & 3, kc2 = g & 1;
    const int k = kc2 * 32 + slotk(q, j);
    const int m = mc * 16 + l;
    float acc = 0.f;
    if (k < 16 || k >= 32) {
      const int sk = s ? 1 : 3;
      const float* src = (k < 16) ? (mw2 + sk * 512 + k * 32)
                       : (k < 48) ? (mw2 + 5 * 512 + (k - 32) * 32)
                                  : (mw2 + 0 * 512 + (k - 48) * 32);
      const float* wrow = ww1 + m;
#pragma unroll
      for (int n = 0; n < 32; n++)
        acc = __builtin_fmaf(src[n], wrow[n * 64], acc);
      if (k < 16) acc = -acc;   // sign applied once (bit-identical to R19 sum)
    }
    ws16[(32 + g) * 512 + r] = us16(acc);
  }
}

// ---------------- main kernel ----------------------------------------------
__global__ __launch_bounds__(256, 2) void point_attn_kernel(
    const float* __restrict__ center, const float* __restrict__ other,
    const float* __restrict__ wb2,
    const unsigned short* __restrict__ ws16, const float* __restrict__ wsf,
    float* __restrict__ out, int P) {
  // pr rows: dwords 0..31 = products (32 ch), dwords 32..35 = staged
  // {d0,d1,d2,d3} row-transport (replaces bpermute gathers).
  __shared__ float pr[256 * 36];
  __shared__ unsigned int d4tab[256];   // staged d4 per row

  const int t = threadIdx.x, lane = t & 63, wv = t >> 6;
  const int q = lane >> 4, l = lane & 15;

  // ---- stage this thread's row into LDS (row r = t) ----
  {
    const int isC = (t >= 240);
    const int pt = isC ? (t - 240) : (t >> 4);
    int p = blockIdx.x * PPB + pt;
    p = p < P ? p : P - 1;
    const float c0 = center[(size_t)p * 3 + 0];
    const float c1 = center[(size_t)p * 3 + 1];
    const float c2 = center[(size_t)p * 3 + 2];
    const float* op = other + ((size_t)p * 16 + (t & 15)) * 3;
    const float o0 = op[0], o1 = op[1], o2 = op[2];
    const float x0 = isC ? c0 : o0, x1 = isC ? c1 : o1, x2 = isC ? c2 : o2;
    const float g0 = c0 - x0, g1 = c1 - x1, g2 = c2 - x2;  // 0 for center rows
    uint4 dd;
    dd.x = pkbf(x0, x1); dd.y = pkbf(x2, g0); dd.z = pkbf(g1, g2);
    dd.w = pkbf(c0, c1);
    *(uint4*)&pr[t * 36 + 32] = dd;          // ds_write_b128
    d4tab[t] = pkbf(c2, 1.0f);               // ds_write_b32
  }
  // No barrier needed: each wave's tiles read only rows staged by the SAME
  // wave (wave wv owns rows wv*64..wv*64+63; tile 15 rows 240..255 = wave 3).
  // Same-wave DS ordering + compiler lgkmcnt give the shuffle-equivalent
  // guarantee.

  // ---- weight/bias registers ----
  bf8 W1[4], W2v[2][2], WC[4][2], P2[2][2];
  f4 bvp[2], b1p[4], b2f[2];

  auto loadSet = [&](int s) {
#pragma unroll
    for (int c = 0; c < 4; c++)
      W1[c] = *(const bf8*)(ws16 + ((s * 4 + c) * 512 + lane * 8));
#pragma unroll
    for (int mc = 0; mc < 2; mc++)
#pragma unroll
      for (int kc2 = 0; kc2 < 2; kc2++)
        W2v[mc][kc2] = *(const bf8*)(ws16 + ((8 + s * 8 + (mc + 2) * 2 + kc2) * 512 + lane * 8));
#pragma unroll
    for (int mc = 0; mc < 4; mc++)
#pragma unroll
      for (int kc2 = 0; kc2 < 2; kc2++)
        WC[mc][kc2] = *(const bf8*)(ws16 + ((32 + s * 8 + mc * 2 + kc2) * 512 + lane * 8));
#pragma unroll
    for (int mc = 0; mc < 2; mc++)
      bvp[mc] = *(const f4*)(wsf + s * 64 + 32 + mc * 16 + q * 4);
#pragma unroll
    for (int mc = 0; mc < 4; mc++)
      b1p[mc] = *(const f4*)(wsf + 128 + s * 64 + mc * 16 + q * 4);
  };

  loadSet(wv == 3 ? 1 : 0);
#pragma unroll
  for (int mc2 = 0; mc2 < 2; mc2++)
#pragma unroll
    for (int kc2 = 0; kc2 < 2; kc2++)
      P2[mc2][kc2] = *(const bf8*)(ws16 + ((28 + mc2 * 2 + kc2) * 512 + lane * 8));
#pragma unroll
  for (int mc2 = 0; mc2 < 2; mc2++) {
    const f4 b = *(const f4*)(wb2 + mc2 * 16 + q * 4);
#pragma unroll
    for (int j = 0; j < 4; j++) b2f[mc2][j] = b[j] * LOG2E;
  }

  auto computeTile = [&](int T) {
    // row transport: b128 read of {d0..d3} + b32 read of d4, then select.
    const int row = T * 16 + l;
    const uint4 g = *(const uint4*)&pr[row * 36 + 32];
    const unsigned int s4 = d4tab[row];
    uint4 bu;
    bu.x = q == 0 ? g.x : (q == 1 ? s4 : 0u);
    bu.y = q == 0 ? g.y : 0u;
    bu.z = q == 0 ? g.z : 0u;
    bu.w = q == 0 ? g.w : 0u;
    const bf8 bx = __builtin_bit_cast(bf8, bu);
    const f4 fzero = {0.f, 0.f, 0.f, 0.f};

    // S1: H^T chunks = [h_k|h_v|h_pos|h_q] (K32, bias in virtual k=9 row)
    f4 D1[4];
#pragma unroll
    for (int c = 0; c < 4; c++)
      D1[c] = lrelu4(mfma32(W1[c], bx, fzero));
    const bf8 hlo = mkbf8(D1[0], D1[1]);
    const bf8 hhi = mkbf8(D1[2], D1[3]);

    // S2vp: vp^T = W2vp^T x H^T, bias in C (independent of S3')
    f4 vpv[2];
#pragma unroll
    for (int mc = 0; mc < 2; mc++) {
      f4 acc = mfma32(W2v[mc][0], hlo, bvp[mc]);
      vpv[mc] = mfma32(W2v[mc][1], hhi, acc);
    }

    // S3' (fused): Hwp^T = WC^T x H^T + b1p  (WP1 folded into W2w in prep)
    f4 h2[4];
#pragma unroll
    for (int mc = 0; mc < 4; mc++) {
      f4 acc = mfma32(WC[mc][1], hhi, b1p[mc]);
      acc = mfma32(WC[mc][0], hlo, acc);
      h2[mc] = lrelu4(acc);
    }
    const bf8 h2lo = mkbf8(h2[0], h2[1]);
    const bf8 h2hi = mkbf8(h2[2], h2[3]);

    // S4: fw^T (log2 domain) = WP2^T x Hwp^T, bias in C
    f4 fw[2];
#pragma unroll
    for (int mc2 = 0; mc2 < 2; mc2++) {
      f4 acc = mfma32(P2[mc2][0], h2lo, b2f[mc2]);
      fw[mc2] = mfma32(P2[mc2][1], h2hi, acc);
    }

    // softmax over 32 channels of row l, base-2 domain, no max-subtraction
    f4 ex0, ex1;
#pragma unroll
    for (int j = 0; j < 4; j++) {
      ex0[j] = exp2appx(fw[0][j]);
      ex1[j] = exp2appx(fw[1][j]);
    }
    const f2 sA = lo2(ex0) + hi2(ex0);
    const f2 sB = lo2(ex1) + hi2(ex1);
    const f2 sC = sA + sB;
    float sum = sC[0] + sC[1];
    sum += __shfl_xor(sum, 16);
    sum += __shfl_xor(sum, 32);
    const float inv = __builtin_amdgcn_rcpf(sum);

    f4 iv; iv[0] = inv; iv[1] = inv; iv[2] = inv; iv[3] = inv;
    const f4 p0 = ex0 * iv * vpv[0];   // packed f32 muls
    const f4 p1 = ex1 * iv * vpv[1];
    *(f4*)&pr[(T * 16 + l) * 36 + q * 4] = p0;        // channels q*4..
    *(f4*)&pr[(T * 16 + l) * 36 + 16 + q * 4] = p1;   // channels 16+q*4..
  };

  // wave 3 does the center tile (15) first with the center weight set
  if (wv == 3) {
    computeTile(15);
    loadSet(0);
    computeTile(12); computeTile(13); computeTile(14);
  } else {
    computeTile(wv * 4 + 0); computeTile(wv * 4 + 1);
    computeTile(wv * 4 + 2); computeTile(wv * 4 + 3);
  }

  __syncthreads();

  // final reduce: 17 rows per point, f2-vectorized (ds_read_b64 + pk_add).
  if (t < 240) {
    const int pp = t >> 4, cp = t & 15;
    f2 s = *(const f2*)&pr[(240 + pp) * 36 + cp * 2];
#pragma unroll
    for (int r2 = 0; r2 < 16; r2++)
      s += *(const f2*)&pr[(pp * 16 + r2) * 36 + cp * 2];
    const int gp = blockIdx.x * PPB + pp;
    if (gp < P) *(f2*)&out[(size_t)gp * 32 + cp * 2] = s;
  }
}

extern "C" void kernel_launch(void* const* d_in, const int* in_sizes, int n_in,
                              void* d_out, int out_size, void* d_ws, size_t ws_size,
                              hipStream_t stream) {
  const float* center = (const float*)d_in[0];
  const float* other  = (const float*)d_in[1];
  unsigned short* ws16 = (unsigned short*)d_ws;
  float* wsf = (float*)((char*)d_ws + 49152);

  prep_kernel<<<41, 256, 0, stream>>>(
      (const float*)d_in[2], (const float*)d_in[3],
      (const float*)d_in[4], (const float*)d_in[5],
      (const float*)d_in[6], (const float*)d_in[8],
      (const float*)d_in[7], ws16, wsf);

  const int P = in_sizes[0] / 3;
  const int blocks = (P + PPB - 1) / PPB;
  point_attn_kernel<<<blocks, 256, 0, stream>>>(
      center, other,
      (const float*)d_in[9],
      ws16, wsf, (float*)d_out, P);
}